// Round 6
// baseline (1338.565 us; speedup 1.0000x reference)
//
#include <hip/hip_runtime.h>
#include <hip/hip_bf16.h>
#include <math.h>

// Problem constants: B=16, N=1024, D=1024, all GEMM K = 1024
#define BATCH 16
#define SEQ   1024
#define DIM   1024
#define ROWS  (BATCH*SEQ)          // 16384
#define KD    1024
#define KTILES (KD/32)             // 32

typedef __bf16 bf16_t;
typedef __bf16 bf16x4 __attribute__((ext_vector_type(4)));
typedef __bf16 bf16x8 __attribute__((ext_vector_type(8)));
typedef float  f32x4  __attribute__((ext_vector_type(4)));

__device__ __forceinline__ float gelu_exact(float x) {
    return 0.5f * x * (1.0f + erff(x * 0.70710678118654752f));
}
__device__ __forceinline__ void split2(float v, bf16_t& h, bf16_t& l) {
    h = (bf16_t)v;
    l = (bf16_t)(v - (float)h);
}

// ---------------------------------------------------------------------------
// Fallback fill (ws_size insufficient diagnostic): d_out <- 0
// ---------------------------------------------------------------------------
__global__ __launch_bounds__(256)
void fill0_kernel(float* __restrict__ p, size_t n) {
    const size_t i = (size_t)blockIdx.x * blockDim.x + threadIdx.x;
    const size_t stride = (size_t)gridDim.x * blockDim.x;
    for (size_t j = i; j < n; j += stride) p[j] = 0.0f;
}

// ---------------------------------------------------------------------------
// LayerNorm + bf16 hi/lo split output. One block (256 thr) per row of 1024.
// ---------------------------------------------------------------------------
__global__ __launch_bounds__(256)
void ln_split_kernel(const float* __restrict__ x, const float* __restrict__ g,
                     const float* __restrict__ b,
                     bf16_t* __restrict__ oh, bf16_t* __restrict__ ol) {
    __shared__ float s1[4], s2[4];
    const size_t row = blockIdx.x;
    const int t = threadIdx.x;
    const float4 v = ((const float4*)(x + row * DIM))[t];
    float s  = v.x + v.y + v.z + v.w;
    float ss = v.x*v.x + v.y*v.y + v.z*v.z + v.w*v.w;
    #pragma unroll
    for (int off = 32; off > 0; off >>= 1) {
        s  += __shfl_down(s,  off, 64);
        ss += __shfl_down(ss, off, 64);
    }
    const int wid = t >> 6, lane = t & 63;
    if (lane == 0) { s1[wid] = s; s2[wid] = ss; }
    __syncthreads();
    s  = s1[0] + s1[1] + s1[2] + s1[3];
    ss = s2[0] + s2[1] + s2[2] + s2[3];
    const float mean = s * (1.0f / DIM);
    const float var  = ss * (1.0f / DIM) - mean * mean;
    const float rstd = rsqrtf(var + 1e-5f);
    const float4 gv = ((const float4*)g)[t];
    const float4 bv = ((const float4*)b)[t];
    float o[4];
    o[0] = (v.x - mean) * rstd * gv.x + bv.x;
    o[1] = (v.y - mean) * rstd * gv.y + bv.y;
    o[2] = (v.z - mean) * rstd * gv.z + bv.z;
    o[3] = (v.w - mean) * rstd * gv.w + bv.w;
    bf16x4 h, l;
    #pragma unroll
    for (int i = 0; i < 4; ++i) { bf16_t hh, ll; split2(o[i], hh, ll); h[i] = hh; l[i] = ll; }
    *(bf16x4*)&oh[row * DIM + t * 4] = h;
    *(bf16x4*)&ol[row * DIM + t * 4] = l;
}

// ---------------------------------------------------------------------------
// Row softmax (1024) + hi/lo split output. One block per row.
// ---------------------------------------------------------------------------
__global__ __launch_bounds__(256)
void softmax_split_kernel(const float* __restrict__ sc,
                          bf16_t* __restrict__ ph, bf16_t* __restrict__ pl) {
    __shared__ float sm[4], ssum[4];
    const size_t row = blockIdx.x;
    const int t = threadIdx.x;
    float4 v = ((const float4*)(sc + row * SEQ))[t];
    float m = fmaxf(fmaxf(v.x, v.y), fmaxf(v.z, v.w));
    #pragma unroll
    for (int off = 32; off > 0; off >>= 1) m = fmaxf(m, __shfl_down(m, off, 64));
    const int wid = t >> 6, lane = t & 63;
    if (lane == 0) sm[wid] = m;
    __syncthreads();
    m = fmaxf(fmaxf(sm[0], sm[1]), fmaxf(sm[2], sm[3]));
    v.x = expf(v.x - m); v.y = expf(v.y - m);
    v.z = expf(v.z - m); v.w = expf(v.w - m);
    float s = v.x + v.y + v.z + v.w;
    #pragma unroll
    for (int off = 32; off > 0; off >>= 1) s += __shfl_down(s, off, 64);
    if (lane == 0) ssum[wid] = s;
    __syncthreads();
    s = ssum[0] + ssum[1] + ssum[2] + ssum[3];
    const float inv = 1.0f / s;
    float o[4] = { v.x * inv, v.y * inv, v.z * inv, v.w * inv };
    bf16x4 h, l;
    #pragma unroll
    for (int i = 0; i < 4; ++i) { bf16_t hh, ll; split2(o[i], hh, ll); h[i] = hh; l[i] = ll; }
    *(bf16x4*)&ph[row * SEQ + t * 4] = h;
    *(bf16x4*)&pl[row * SEQ + t * 4] = l;
}

// ---------------------------------------------------------------------------
// Weight transpose + split: w [K=1024][N=1024] fp32 -> wT hi/lo [N][K] bf16.
// ---------------------------------------------------------------------------
__global__ __launch_bounds__(256)
void wsplit_kernel(const float* __restrict__ w,
                   bf16_t* __restrict__ oh, bf16_t* __restrict__ ol) {
    __shared__ float T[64][68];
    const int k0 = blockIdx.x * 64, n0 = blockIdx.y * 64;
    const int t = threadIdx.x;
    const int tr = t >> 4, tc = t & 15;
    #pragma unroll
    for (int j = 0; j < 4; ++j) {
        const float4 v = *(const float4*)&w[(size_t)(k0 + tr + j * 16) * DIM + n0 + tc * 4];
        *(float4*)&T[tr + j * 16][tc * 4] = v;
    }
    __syncthreads();
    #pragma unroll
    for (int j = 0; j < 4; ++j) {
        const int nl = tr + j * 16;     // output row (n)
        const int kl = tc * 4;          // output col group (k)
        bf16x4 h, l;
        #pragma unroll
        for (int i = 0; i < 4; ++i) {
            bf16_t hh, ll; split2(T[kl + i][nl], hh, ll);
            h[i] = hh; l[i] = ll;
        }
        *(bf16x4*)&oh[(size_t)(n0 + nl) * KD + k0 + kl] = h;
        *(bf16x4*)&ol[(size_t)(n0 + nl) * KD + k0 + kl] = l;
    }
}

// ---------------------------------------------------------------------------
// bf16x3 split MFMA GEMM (always NT):
//   C[m][n] = epi( scale * sum_k A[m][k]*B'[n][k] )
// Tile 128x128, BK=32, 256 thr = 4 waves (2x2), 4x4 16x16x32 frags per wave.
// 3 MFMAs per frag-pair: hi*hi + hi*lo + lo*hi (drops lo*lo ~2^-16).
// LDS chunk-swizzle on 16B chunks within 64B rows (write AND read -> safe).
// BIAS: 0 none, 1 per-col, 2 per-row. SPLIT: write Ch/Cl bf16 hi/lo, else Cf.
// RES: add res fp32 after GELU. (No buffer is both read and written anywhere
// in the launch sequence; Cf/res left non-restrict as belt-and-braces.)
// ---------------------------------------------------------------------------
template<int BIAS, bool GELU, bool SPLIT, bool RES>
__global__ __launch_bounds__(256)
void gemm_mfma(const bf16_t* __restrict__ Ah, const bf16_t* __restrict__ Al,
               const bf16_t* __restrict__ Bh, const bf16_t* __restrict__ Bl,
               const float* __restrict__ bias, const float* res,
               float* Cf, bf16_t* __restrict__ Ch, bf16_t* __restrict__ Cl,
               int Nn, int ldb,
               long long sA, long long sB, long long sC, float scale) {
    __shared__ alignas(16) bf16_t LAh[128 * 32];
    __shared__ alignas(16) bf16_t LAl[128 * 32];
    __shared__ alignas(16) bf16_t LBh[128 * 32];
    __shared__ alignas(16) bf16_t LBl[128 * 32];

    const int bm0 = blockIdx.x * 128;
    const int bn0 = blockIdx.y * 128;
    const int bz  = blockIdx.z;
    Ah += (size_t)bz * sA;  Al += (size_t)bz * sA;
    Bh += (size_t)bz * sB;  Bl += (size_t)bz * sB;
    const size_t cbase = (size_t)bz * sC;

    const int tid  = threadIdx.x;
    const int lane = tid & 63;
    const int w    = tid >> 6;
    const int wm   = w >> 1, wn = w & 1;

    // ---- staging: thread owns 16B chunks i0=tid, i1=tid+256 of each buffer
    const int r0 = tid >> 2;          // tile row 0..63
    const int g0 = tid & 3;           // k-chunk 0..3
    const int r1 = r0 + 64;
    const bf16_t* pAh0 = Ah + (size_t)(bm0 + r0) * KD + g0 * 8;
    const bf16_t* pAh1 = pAh0 + (size_t)64 * KD;
    const bf16_t* pAl0 = Al + (size_t)(bm0 + r0) * KD + g0 * 8;
    const bf16_t* pAl1 = pAl0 + (size_t)64 * KD;
    const bf16_t* pBh0 = Bh + (size_t)(bn0 + r0) * ldb + g0 * 8;
    const bf16_t* pBh1 = pBh0 + (size_t)64 * ldb;
    const bf16_t* pBl0 = Bl + (size_t)(bn0 + r0) * ldb + g0 * 8;
    const bf16_t* pBl1 = pBl0 + (size_t)64 * ldb;
    // swizzled LDS write offsets (elements)
    const int lw0 = r0 * 32 + ((g0 ^ ((r0 >> 1) & 3)) * 8);
    const int lw1 = r1 * 32 + ((g0 ^ ((r1 >> 1) & 3)) * 8);

    // ---- fragment read offsets (elements), same swizzle
    int roffA[4], roffB[4];
    #pragma unroll
    for (int i = 0; i < 4; ++i) {
        const int ra = wm * 64 + i * 16 + (lane & 15);
        roffA[i] = ra * 32 + (((lane >> 4) ^ ((ra >> 1) & 3)) * 8);
        const int rb = wn * 64 + i * 16 + (lane & 15);
        roffB[i] = rb * 32 + (((lane >> 4) ^ ((rb >> 1) & 3)) * 8);
    }

    f32x4 acc[4][4];
    #pragma unroll
    for (int i = 0; i < 4; ++i)
        #pragma unroll
        for (int j = 0; j < 4; ++j)
            acc[i][j] = (f32x4)0.0f;

    // prologue: load tile 0 into regs
    uint4 vAh0 = *(const uint4*)pAh0, vAh1 = *(const uint4*)pAh1;
    uint4 vAl0 = *(const uint4*)pAl0, vAl1 = *(const uint4*)pAl1;
    uint4 vBh0 = *(const uint4*)pBh0, vBh1 = *(const uint4*)pBh1;
    uint4 vBl0 = *(const uint4*)pBl0, vBl1 = *(const uint4*)pBl1;

    for (int kt = 0; kt < KTILES; ++kt) {
        __syncthreads();                       // prev frag reads done
        *(uint4*)&LAh[lw0] = vAh0;  *(uint4*)&LAh[lw1] = vAh1;
        *(uint4*)&LAl[lw0] = vAl0;  *(uint4*)&LAl[lw1] = vAl1;
        *(uint4*)&LBh[lw0] = vBh0;  *(uint4*)&LBh[lw1] = vBh1;
        *(uint4*)&LBl[lw0] = vBl0;  *(uint4*)&LBl[lw1] = vBl1;
        __syncthreads();                       // tile visible
        if (kt < KTILES - 1) {                 // prefetch next tile (overlaps MFMA)
            pAh0 += 32; pAh1 += 32; pAl0 += 32; pAl1 += 32;
            pBh0 += 32; pBh1 += 32; pBl0 += 32; pBl1 += 32;
            vAh0 = *(const uint4*)pAh0; vAh1 = *(const uint4*)pAh1;
            vAl0 = *(const uint4*)pAl0; vAl1 = *(const uint4*)pAl1;
            vBh0 = *(const uint4*)pBh0; vBh1 = *(const uint4*)pBh1;
            vBl0 = *(const uint4*)pBl0; vBl1 = *(const uint4*)pBl1;
        }
        bf16x8 bh[4], bl[4];
        #pragma unroll
        for (int i = 0; i < 4; ++i) {
            bh[i] = *(const bf16x8*)&LBh[roffB[i]];
            bl[i] = *(const bf16x8*)&LBl[roffB[i]];
        }
        #pragma unroll
        for (int im = 0; im < 4; ++im) {
            const bf16x8 ah = *(const bf16x8*)&LAh[roffA[im]];
            const bf16x8 al = *(const bf16x8*)&LAl[roffA[im]];
            #pragma unroll
            for (int in = 0; in < 4; ++in) {
                acc[im][in] = __builtin_amdgcn_mfma_f32_16x16x32_bf16(ah, bh[in], acc[im][in], 0, 0, 0);
                acc[im][in] = __builtin_amdgcn_mfma_f32_16x16x32_bf16(ah, bl[in], acc[im][in], 0, 0, 0);
                acc[im][in] = __builtin_amdgcn_mfma_f32_16x16x32_bf16(al, bh[in], acc[im][in], 0, 0, 0);
            }
        }
    }

    // ---- epilogue: D col = lane&15, row = 4*(lane>>4)+j  (guide-verified)
    const int colb = bn0 + wn * 64 + (lane & 15);
    const int rowb = bm0 + wm * 64 + 4 * (lane >> 4);
    #pragma unroll
    for (int im = 0; im < 4; ++im) {
        #pragma unroll
        for (int in = 0; in < 4; ++in) {
            const int col = colb + in * 16;
            float bc = 0.0f;
            if (BIAS == 1) bc = bias[col];
            #pragma unroll
            for (int j = 0; j < 4; ++j) {
                const int row = rowb + im * 16 + j;
                float v = acc[im][in][j] * scale;
                if (BIAS == 1) v += bc;
                if (BIAS == 2) v += bias[row];
                if (GELU) v = gelu_exact(v);
                const size_t off = cbase + (size_t)row * Nn + col;
                if (SPLIT) {
                    bf16_t hh, ll; split2(v, hh, ll);
                    Ch[off] = hh; Cl[off] = ll;
                } else {
                    if (RES) v += res[off];
                    Cf[off] = v;
                }
            }
        }
    }
}

// ---------------------------------------------------------------------------
// Workspace budget (216 MB), liveness-audited:
//   S0 (64MB): xn -> scores(fp32) -> attV -> xu          ws + 0
//   S1 (64MB): q  -> p -> x_update(fp32)                 ws + 2*EL
//   S2 (64MB): vT -> h1                                  ws + 4*EL
//   Wb (24MB): 6 transposed+split weights                ws + 6*EL
//   K  (64MB): borrows d_out (dead after step 6; d_out fully rewritten at 12)
// No buffer is both read and written by any single kernel launch.
// ---------------------------------------------------------------------------
extern "C" void kernel_launch(void* const* d_in, const int* in_sizes, int n_in,
                              void* d_out, int out_size, void* d_ws, size_t ws_size,
                              hipStream_t stream) {
    const float* x     = (const float*)d_in[0];
    const float* ln1_g = (const float*)d_in[1];
    const float* ln1_b = (const float*)d_in[2];
    const float* ln2_g = (const float*)d_in[3];
    const float* ln2_b = (const float*)d_in[4];
    const float* wq    = (const float*)d_in[5];
    const float* bq    = (const float*)d_in[6];
    const float* wk    = (const float*)d_in[7];
    const float* bk    = (const float*)d_in[8];
    const float* wv    = (const float*)d_in[9];
    const float* bv    = (const float*)d_in[10];
    const float* wo    = (const float*)d_in[11];
    const float* bo    = (const float*)d_in[12];
    const float* w1    = (const float*)d_in[13];
    const float* b1    = (const float*)d_in[14];
    const float* w2    = (const float*)d_in[15];
    const float* b2    = (const float*)d_in[16];

    const size_t EL  = (size_t)ROWS * DIM;      // 16M elems
    const size_t WEL = (size_t)DIM * KD;        // 1M elems
    const size_t NEED = (6 * EL + 12 * WEL) * sizeof(bf16_t);   // 216 MB

    if (ws_size < NEED) {
        // Diagnostic fallback: clean wrong-answer (fast, no fault) instead of
        // an OOB crash — distinguishes "ws too small" from a kernel bug.
        fill0_kernel<<<2048, 256, 0, stream>>>((float*)d_out, (size_t)out_size);
        return;
    }

    bf16_t* base = (bf16_t*)d_ws;
    bf16_t* S0h = base;            bf16_t* S0l = S0h + EL;   // xn / sc / attV / xu
    bf16_t* S1h = base + 2 * EL;   bf16_t* S1l = S1h + EL;   // q / p / x_update
    bf16_t* S2h = base + 4 * EL;   bf16_t* S2l = S2h + EL;   // vT / h1
    bf16_t* Wb  = base + 6 * EL;                             // 6 x (1M hi + 1M lo)
    bf16_t* Kh  = (bf16_t*)d_out;  bf16_t* Kl = Kh + EL;     // k borrows d_out
    float* sc   = (float*)S0h;                               // 16M fp32 = S0h+S0l
    float* xupd = (float*)S1h;                               // 16M fp32 = S1h+S1l

    const dim3 blk(256);
    const dim3 gw(ROWS / 128, DIM / 128, 1);     // weight GEMMs: 128 x 8
    const dim3 gvt(DIM / 128, ROWS / 128, 1);    // vT GEMM:      8 x 128
    const dim3 ga(SEQ / 128, SEQ / 128, BATCH);  // attn GEMMs:   8 x 8 x 16
    const long long sND = (long long)SEQ * DIM;  // 1M
    const long long sNN = (long long)SEQ * SEQ;  // 1M

    // 1. xn = LN1(x)  (split) -> S0
    ln_split_kernel<<<ROWS, blk, 0, stream>>>(x, ln1_g, ln1_b, S0h, S0l);
    // 2. transpose+split the 6 weights -> [N][K] hi/lo
    const float* Wsrc[6] = { wq, wk, wv, wo, w1, w2 };
    bf16_t *wTh[6], *wTl[6];
    for (int i = 0; i < 6; ++i) {
        wTh[i] = Wb + (size_t)i * 2 * WEL;
        wTl[i] = wTh[i] + WEL;
        wsplit_kernel<<<dim3(16, 16), blk, 0, stream>>>(Wsrc[i], wTh[i], wTl[i]);
    }
    // 3. q = xn @ wq + bq  -> S1
    gemm_mfma<1, false, true, false><<<gw, blk, 0, stream>>>(
        S0h, S0l, wTh[0], wTl[0], bq, nullptr, nullptr, S1h, S1l, DIM, KD, 0, 0, 0, 1.0f);
    // 4. k = xn @ wk + bk  -> d_out (Kh/Kl)
    gemm_mfma<1, false, true, false><<<gw, blk, 0, stream>>>(
        S0h, S0l, wTh[1], wTl[1], bk, nullptr, nullptr, Kh, Kl, DIM, KD, 0, 0, 0, 1.0f);
    // 5. vT = (xn @ wv + bv)^T = wvT @ xn^T  (bias per-row) -> S2 [DIM][ROWS]
    gemm_mfma<2, false, true, false><<<gvt, blk, 0, stream>>>(
        wTh[2], wTl[2], S0h, S0l, bv, nullptr, nullptr, S2h, S2l, ROWS, KD, 0, 0, 0, 1.0f);
    // 6. scores = q @ k^T / 32  (batched, fp32) -> sc (S0; xn dead)
    gemm_mfma<0, false, false, false><<<ga, blk, 0, stream>>>(
        S1h, S1l, Kh, Kl, nullptr, nullptr, sc, nullptr, nullptr, SEQ, KD, sND, sND, sNN, 0.03125f);
    // 7. p = softmax(sc)  -> S1 (q dead)
    softmax_split_kernel<<<ROWS, blk, 0, stream>>>(sc, S1h, S1l);
    // 8. attV = p @ vT^T  (batched; B = vT + bz*1024, ldb=ROWS) -> S0 (sc dead)
    gemm_mfma<0, false, true, false><<<ga, blk, 0, stream>>>(
        S1h, S1l, S2h, S2l, nullptr, nullptr, nullptr, S0h, S0l, DIM, ROWS, sNN, SEQ, sND, 1.0f);
    // 9. x_update = attV @ wo + bo + x  -> xupd in ws (S1; p dead)
    gemm_mfma<1, false, false, true><<<gw, blk, 0, stream>>>(
        S0h, S0l, wTh[3], wTl[3], bo, x, xupd, nullptr, nullptr, DIM, KD, 0, 0, 0, 1.0f);
    // 10. xu = LN2(x_update)  -> S0 (attV dead)
    ln_split_kernel<<<ROWS, blk, 0, stream>>>(xupd, ln2_g, ln2_b, S0h, S0l);
    // 11. h1 = gelu(xu @ w1 + b1)  -> S2 (vT dead)
    gemm_mfma<1, true, true, false><<<gw, blk, 0, stream>>>(
        S0h, S0l, wTh[4], wTl[4], b1, nullptr, nullptr, S2h, S2l, DIM, KD, 0, 0, 0, 1.0f);
    // 12. out = gelu(h1 @ w2 + b2) + x_update  -> d_out (single full write)
    gemm_mfma<1, true, false, true><<<gw, blk, 0, stream>>>(
        S2h, S2l, wTh[5], wTl[5], b2, xupd, (float*)d_out, nullptr, nullptr, DIM, KD, 0, 0, 0, 1.0f);
}

// Round 7
// 1217.465 us; speedup vs baseline: 1.0995x; 1.0995x over previous
//
#include <hip/hip_runtime.h>
#include <hip/hip_bf16.h>
#include <math.h>

// Problem constants: B=16, N=1024, D=1024, all GEMM K = 1024
#define BATCH 16
#define SEQ   1024
#define DIM   1024
#define ROWS  (BATCH*SEQ)          // 16384
#define KD    1024
#define KTILES (KD/32)             // 32

typedef __bf16 bf16_t;
typedef __bf16 bf16x4 __attribute__((ext_vector_type(4)));
typedef __bf16 bf16x8 __attribute__((ext_vector_type(8)));
typedef float  f32x4  __attribute__((ext_vector_type(4)));

__device__ __forceinline__ float gelu_exact(float x) {
    return 0.5f * x * (1.0f + erff(x * 0.70710678118654752f));
}
__device__ __forceinline__ void split2(float v, bf16_t& h, bf16_t& l) {
    h = (bf16_t)v;
    l = (bf16_t)(v - (float)h);
}

// async global->LDS, 16B per lane. dst must be wave-uniform base; HW adds lane*16.
__device__ __forceinline__ void gload16(const bf16_t* g, bf16_t* l) {
    __builtin_amdgcn_global_load_lds(
        (const __attribute__((address_space(1))) unsigned int*)g,
        (__attribute__((address_space(3))) unsigned int*)l,
        16, 0, 0);
}

// ---------------------------------------------------------------------------
// Fallback fill (ws_size insufficient diagnostic): d_out <- 0
// ---------------------------------------------------------------------------
__global__ __launch_bounds__(256)
void fill0_kernel(float* __restrict__ p, size_t n) {
    const size_t i = (size_t)blockIdx.x * blockDim.x + threadIdx.x;
    const size_t stride = (size_t)gridDim.x * blockDim.x;
    for (size_t j = i; j < n; j += stride) p[j] = 0.0f;
}

// ---------------------------------------------------------------------------
// LayerNorm + bf16 hi/lo split output. One block (256 thr) per row of 1024.
// ---------------------------------------------------------------------------
__global__ __launch_bounds__(256)
void ln_split_kernel(const float* __restrict__ x, const float* __restrict__ g,
                     const float* __restrict__ b,
                     bf16_t* __restrict__ oh, bf16_t* __restrict__ ol) {
    __shared__ float s1[4], s2[4];
    const size_t row = blockIdx.x;
    const int t = threadIdx.x;
    const float4 v = ((const float4*)(x + row * DIM))[t];
    float s  = v.x + v.y + v.z + v.w;
    float ss = v.x*v.x + v.y*v.y + v.z*v.z + v.w*v.w;
    #pragma unroll
    for (int off = 32; off > 0; off >>= 1) {
        s  += __shfl_down(s,  off, 64);
        ss += __shfl_down(ss, off, 64);
    }
    const int wid = t >> 6, lane = t & 63;
    if (lane == 0) { s1[wid] = s; s2[wid] = ss; }
    __syncthreads();
    s  = s1[0] + s1[1] + s1[2] + s1[3];
    ss = s2[0] + s2[1] + s2[2] + s2[3];
    const float mean = s * (1.0f / DIM);
    const float var  = ss * (1.0f / DIM) - mean * mean;
    const float rstd = rsqrtf(var + 1e-5f);
    const float4 gv = ((const float4*)g)[t];
    const float4 bv = ((const float4*)b)[t];
    float o[4];
    o[0] = (v.x - mean) * rstd * gv.x + bv.x;
    o[1] = (v.y - mean) * rstd * gv.y + bv.y;
    o[2] = (v.z - mean) * rstd * gv.z + bv.z;
    o[3] = (v.w - mean) * rstd * gv.w + bv.w;
    bf16x4 h, l;
    #pragma unroll
    for (int i = 0; i < 4; ++i) { bf16_t hh, ll; split2(o[i], hh, ll); h[i] = hh; l[i] = ll; }
    *(bf16x4*)&oh[row * DIM + t * 4] = h;
    *(bf16x4*)&ol[row * DIM + t * 4] = l;
}

// ---------------------------------------------------------------------------
// Row softmax (1024) + hi/lo split output. One block per row.
// ---------------------------------------------------------------------------
__global__ __launch_bounds__(256)
void softmax_split_kernel(const float* __restrict__ sc,
                          bf16_t* __restrict__ ph, bf16_t* __restrict__ pl) {
    __shared__ float sm[4], ssum[4];
    const size_t row = blockIdx.x;
    const int t = threadIdx.x;
    float4 v = ((const float4*)(sc + row * SEQ))[t];
    float m = fmaxf(fmaxf(v.x, v.y), fmaxf(v.z, v.w));
    #pragma unroll
    for (int off = 32; off > 0; off >>= 1) m = fmaxf(m, __shfl_down(m, off, 64));
    const int wid = t >> 6, lane = t & 63;
    if (lane == 0) sm[wid] = m;
    __syncthreads();
    m = fmaxf(fmaxf(sm[0], sm[1]), fmaxf(sm[2], sm[3]));
    v.x = expf(v.x - m); v.y = expf(v.y - m);
    v.z = expf(v.z - m); v.w = expf(v.w - m);
    float s = v.x + v.y + v.z + v.w;
    #pragma unroll
    for (int off = 32; off > 0; off >>= 1) s += __shfl_down(s, off, 64);
    if (lane == 0) ssum[wid] = s;
    __syncthreads();
    s = ssum[0] + ssum[1] + ssum[2] + ssum[3];
    const float inv = 1.0f / s;
    float o[4] = { v.x * inv, v.y * inv, v.z * inv, v.w * inv };
    bf16x4 h, l;
    #pragma unroll
    for (int i = 0; i < 4; ++i) { bf16_t hh, ll; split2(o[i], hh, ll); h[i] = hh; l[i] = ll; }
    *(bf16x4*)&ph[row * SEQ + t * 4] = h;
    *(bf16x4*)&pl[row * SEQ + t * 4] = l;
}

// ---------------------------------------------------------------------------
// Weight transpose + split: w [K=1024][N=1024] fp32 -> wT hi/lo [N][K] bf16.
// ---------------------------------------------------------------------------
__global__ __launch_bounds__(256)
void wsplit_kernel(const float* __restrict__ w,
                   bf16_t* __restrict__ oh, bf16_t* __restrict__ ol) {
    __shared__ float T[64][68];
    const int k0 = blockIdx.x * 64, n0 = blockIdx.y * 64;
    const int t = threadIdx.x;
    const int tr = t >> 4, tc = t & 15;
    #pragma unroll
    for (int j = 0; j < 4; ++j) {
        const float4 v = *(const float4*)&w[(size_t)(k0 + tr + j * 16) * DIM + n0 + tc * 4];
        *(float4*)&T[tr + j * 16][tc * 4] = v;
    }
    __syncthreads();
    #pragma unroll
    for (int j = 0; j < 4; ++j) {
        const int nl = tr + j * 16;     // output row (n)
        const int kl = tc * 4;          // output col group (k)
        bf16x4 h, l;
        #pragma unroll
        for (int i = 0; i < 4; ++i) {
            bf16_t hh, ll; split2(T[kl + i][nl], hh, ll);
            h[i] = hh; l[i] = ll;
        }
        *(bf16x4*)&oh[(size_t)(n0 + nl) * KD + k0 + kl] = h;
        *(bf16x4*)&ol[(size_t)(n0 + nl) * KD + k0 + kl] = l;
    }
}

// ---------------------------------------------------------------------------
// bf16x3 split MFMA GEMM (always NT):
//   C[m][n] = epi( scale * sum_k A[m][k]*B'[n][k] )
// Tile 128x128, BK=32, 256 thr = 4 waves (2x2), 4x4 16x16x32 frags per wave.
// 3 MFMAs per frag-pair: hi*hi + hi*lo + lo*hi (drops lo*lo ~2^-16).
// Staging: global_load_lds width=16 (no VGPR round-trip). LDS dest is LINEAR
// (HW: wave-uniform base + lane*16B -> row-major [r][32]); the bank-conflict
// swizzle is applied on the GLOBAL SOURCE chunk (c ^ ((r>>1)&3)) and the same
// XOR on the read side (rule: both-sides-or-neither; layout is bit-identical
// to the previous reg-staged version -> numerics unchanged).
// BIAS: 0 none, 1 per-col, 2 per-row. SPLIT: write Ch/Cl bf16 hi/lo, else Cf.
// RES: add res fp32 after GELU. (No buffer is both read and written by any
// launch in the sequence; Cf/res left non-restrict as belt-and-braces.)
// ---------------------------------------------------------------------------
template<int BIAS, bool GELU, bool SPLIT, bool RES>
__global__ __launch_bounds__(256)
void gemm_mfma(const bf16_t* __restrict__ Ah, const bf16_t* __restrict__ Al,
               const bf16_t* __restrict__ Bh, const bf16_t* __restrict__ Bl,
               const float* __restrict__ bias, const float* res,
               float* Cf, bf16_t* __restrict__ Ch, bf16_t* __restrict__ Cl,
               int Nn, int ldb,
               long long sA, long long sB, long long sC, float scale) {
    __shared__ alignas(16) bf16_t LAh[128 * 32];
    __shared__ alignas(16) bf16_t LAl[128 * 32];
    __shared__ alignas(16) bf16_t LBh[128 * 32];
    __shared__ alignas(16) bf16_t LBl[128 * 32];

    const int bm0 = blockIdx.x * 128;
    const int bn0 = blockIdx.y * 128;
    const int bz  = blockIdx.z;
    Ah += (size_t)bz * sA;  Al += (size_t)bz * sA;
    Bh += (size_t)bz * sB;  Bl += (size_t)bz * sB;
    const size_t cbase = (size_t)bz * sC;

    const int tid  = threadIdx.x;
    const int lane = tid & 63;
    const int w    = tid >> 6;
    const int wm   = w >> 1, wn = w & 1;

    // ---- async staging geometry: wave w, issue i covers rows [i*64+w*16, +16)
    // lane l -> local row (l>>2), chunk c = l&3; source chunk is swizzled.
    const int rr0 = w * 16 + (lane >> 2);        // issue-0 tile row
    const int rr1 = rr0 + 64;                    // issue-1 tile row
    const int c   = lane & 3;
    const int cs0 = c ^ ((rr0 >> 1) & 3);        // pre-swizzled source chunk
    const int cs1 = c ^ ((rr1 >> 1) & 3);
    const int ldst0 = (w * 16) * 32;             // wave-uniform LDS elem offset
    const int ldst1 = (64 + w * 16) * 32;

    const bf16_t* gAh0 = Ah + (size_t)(bm0 + rr0) * KD + cs0 * 8;
    const bf16_t* gAh1 = Ah + (size_t)(bm0 + rr1) * KD + cs1 * 8;
    const bf16_t* gAl0 = Al + (size_t)(bm0 + rr0) * KD + cs0 * 8;
    const bf16_t* gAl1 = Al + (size_t)(bm0 + rr1) * KD + cs1 * 8;
    const bf16_t* gBh0 = Bh + (size_t)(bn0 + rr0) * ldb + cs0 * 8;
    const bf16_t* gBh1 = Bh + (size_t)(bn0 + rr1) * ldb + cs1 * 8;
    const bf16_t* gBl0 = Bl + (size_t)(bn0 + rr0) * ldb + cs0 * 8;
    const bf16_t* gBl1 = Bl + (size_t)(bn0 + rr1) * ldb + cs1 * 8;

    // ---- fragment read offsets (elements), same XOR swizzle as source
    int roffA[4], roffB[4];
    #pragma unroll
    for (int i = 0; i < 4; ++i) {
        const int ra = wm * 64 + i * 16 + (lane & 15);
        roffA[i] = ra * 32 + (((lane >> 4) ^ ((ra >> 1) & 3)) * 8);
        const int rb = wn * 64 + i * 16 + (lane & 15);
        roffB[i] = rb * 32 + (((lane >> 4) ^ ((rb >> 1) & 3)) * 8);
    }

    f32x4 acc[4][4];
    #pragma unroll
    for (int i = 0; i < 4; ++i)
        #pragma unroll
        for (int j = 0; j < 4; ++j)
            acc[i][j] = (f32x4)0.0f;

    for (int kt = 0; kt < KTILES; ++kt) {
        // issue async global->LDS for this K-tile (8 instrs/wave)
        gload16(gAh0, &LAh[ldst0]);  gload16(gAh1, &LAh[ldst1]);
        gload16(gAl0, &LAl[ldst0]);  gload16(gAl1, &LAl[ldst1]);
        gload16(gBh0, &LBh[ldst0]);  gload16(gBh1, &LBh[ldst1]);
        gload16(gBl0, &LBl[ldst0]);  gload16(gBl1, &LBl[ldst1]);
        gAh0 += 32; gAh1 += 32; gAl0 += 32; gAl1 += 32;
        gBh0 += 32; gBh1 += 32; gBl0 += 32; gBl1 += 32;
        __syncthreads();                       // drains vmcnt -> tile visible

        bf16x8 bh[4], bl[4];
        #pragma unroll
        for (int i = 0; i < 4; ++i) {
            bh[i] = *(const bf16x8*)&LBh[roffB[i]];
            bl[i] = *(const bf16x8*)&LBl[roffB[i]];
        }
        #pragma unroll
        for (int im = 0; im < 4; ++im) {
            const bf16x8 ah = *(const bf16x8*)&LAh[roffA[im]];
            const bf16x8 al = *(const bf16x8*)&LAl[roffA[im]];
            #pragma unroll
            for (int in = 0; in < 4; ++in) {
                acc[im][in] = __builtin_amdgcn_mfma_f32_16x16x32_bf16(ah, bh[in], acc[im][in], 0, 0, 0);
                acc[im][in] = __builtin_amdgcn_mfma_f32_16x16x32_bf16(ah, bl[in], acc[im][in], 0, 0, 0);
                acc[im][in] = __builtin_amdgcn_mfma_f32_16x16x32_bf16(al, bh[in], acc[im][in], 0, 0, 0);
            }
        }
        __syncthreads();                       // reads done before next writes
    }

    // ---- epilogue: D col = lane&15, row = 4*(lane>>4)+j  (guide-verified)
    const int colb = bn0 + wn * 64 + (lane & 15);
    const int rowb = bm0 + wm * 64 + 4 * (lane >> 4);
    #pragma unroll
    for (int im = 0; im < 4; ++im) {
        #pragma unroll
        for (int in = 0; in < 4; ++in) {
            const int col = colb + in * 16;
            float bc = 0.0f;
            if (BIAS == 1) bc = bias[col];
            #pragma unroll
            for (int j = 0; j < 4; ++j) {
                const int row = rowb + im * 16 + j;
                float v = acc[im][in][j] * scale;
                if (BIAS == 1) v += bc;
                if (BIAS == 2) v += bias[row];
                if (GELU) v = gelu_exact(v);
                const size_t off = cbase + (size_t)row * Nn + col;
                if (SPLIT) {
                    bf16_t hh, ll; split2(v, hh, ll);
                    Ch[off] = hh; Cl[off] = ll;
                } else {
                    if (RES) v += res[off];
                    Cf[off] = v;
                }
            }
        }
    }
}

// ---------------------------------------------------------------------------
// Workspace budget (216 MB), liveness-audited:
//   S0 (64MB): xn -> scores(fp32) -> attV -> xu          ws + 0
//   S1 (64MB): q  -> p -> x_update(fp32)                 ws + 2*EL
//   S2 (64MB): vT -> h1                                  ws + 4*EL
//   Wb (24MB): 6 transposed+split weights                ws + 6*EL
//   K  (64MB): borrows d_out (dead after step 6; d_out fully rewritten at 12)
// No buffer is both read and written by any single kernel launch.
// ---------------------------------------------------------------------------
extern "C" void kernel_launch(void* const* d_in, const int* in_sizes, int n_in,
                              void* d_out, int out_size, void* d_ws, size_t ws_size,
                              hipStream_t stream) {
    const float* x     = (const float*)d_in[0];
    const float* ln1_g = (const float*)d_in[1];
    const float* ln1_b = (const float*)d_in[2];
    const float* ln2_g = (const float*)d_in[3];
    const float* ln2_b = (const float*)d_in[4];
    const float* wq    = (const float*)d_in[5];
    const float* bq    = (const float*)d_in[6];
    const float* wk    = (const float*)d_in[7];
    const float* bk    = (const float*)d_in[8];
    const float* wv    = (const float*)d_in[9];
    const float* bv    = (const float*)d_in[10];
    const float* wo    = (const float*)d_in[11];
    const float* bo    = (const float*)d_in[12];
    const float* w1    = (const float*)d_in[13];
    const float* b1    = (const float*)d_in[14];
    const float* w2    = (const float*)d_in[15];
    const float* b2    = (const float*)d_in[16];

    const size_t EL  = (size_t)ROWS * DIM;      // 16M elems
    const size_t WEL = (size_t)DIM * KD;        // 1M elems
    const size_t NEED = (6 * EL + 12 * WEL) * sizeof(bf16_t);   // 216 MB

    if (ws_size < NEED) {
        fill0_kernel<<<2048, 256, 0, stream>>>((float*)d_out, (size_t)out_size);
        return;
    }

    bf16_t* base = (bf16_t*)d_ws;
    bf16_t* S0h = base;            bf16_t* S0l = S0h + EL;   // xn / sc / attV / xu
    bf16_t* S1h = base + 2 * EL;   bf16_t* S1l = S1h + EL;   // q / p / x_update
    bf16_t* S2h = base + 4 * EL;   bf16_t* S2l = S2h + EL;   // vT / h1
    bf16_t* Wb  = base + 6 * EL;                             // 6 x (1M hi + 1M lo)
    bf16_t* Kh  = (bf16_t*)d_out;  bf16_t* Kl = Kh + EL;     // k borrows d_out
    float* sc   = (float*)S0h;                               // 16M fp32 = S0h+S0l
    float* xupd = (float*)S1h;                               // 16M fp32 = S1h+S1l

    const dim3 blk(256);
    const dim3 gw(ROWS / 128, DIM / 128, 1);     // weight GEMMs: 128 x 8
    const dim3 gvt(DIM / 128, ROWS / 128, 1);    // vT GEMM:      8 x 128
    const dim3 ga(SEQ / 128, SEQ / 128, BATCH);  // attn GEMMs:   8 x 8 x 16
    const long long sND = (long long)SEQ * DIM;  // 1M
    const long long sNN = (long long)SEQ * SEQ;  // 1M

    // 1. xn = LN1(x)  (split) -> S0
    ln_split_kernel<<<ROWS, blk, 0, stream>>>(x, ln1_g, ln1_b, S0h, S0l);
    // 2. transpose+split the 6 weights -> [N][K] hi/lo
    const float* Wsrc[6] = { wq, wk, wv, wo, w1, w2 };
    bf16_t *wTh[6], *wTl[6];
    for (int i = 0; i < 6; ++i) {
        wTh[i] = Wb + (size_t)i * 2 * WEL;
        wTl[i] = wTh[i] + WEL;
        wsplit_kernel<<<dim3(16, 16), blk, 0, stream>>>(Wsrc[i], wTh[i], wTl[i]);
    }
    // 3. q = xn @ wq + bq  -> S1
    gemm_mfma<1, false, true, false><<<gw, blk, 0, stream>>>(
        S0h, S0l, wTh[0], wTl[0], bq, nullptr, nullptr, S1h, S1l, DIM, KD, 0, 0, 0, 1.0f);
    // 4. k = xn @ wk + bk  -> d_out (Kh/Kl)
    gemm_mfma<1, false, true, false><<<gw, blk, 0, stream>>>(
        S0h, S0l, wTh[1], wTl[1], bk, nullptr, nullptr, Kh, Kl, DIM, KD, 0, 0, 0, 1.0f);
    // 5. vT = (xn @ wv + bv)^T = wvT @ xn^T  (bias per-row) -> S2 [DIM][ROWS]
    gemm_mfma<2, false, true, false><<<gvt, blk, 0, stream>>>(
        wTh[2], wTl[2], S0h, S0l, bv, nullptr, nullptr, S2h, S2l, ROWS, KD, 0, 0, 0, 1.0f);
    // 6. scores = q @ k^T / 32  (batched, fp32) -> sc (S0; xn dead)
    gemm_mfma<0, false, false, false><<<ga, blk, 0, stream>>>(
        S1h, S1l, Kh, Kl, nullptr, nullptr, sc, nullptr, nullptr, SEQ, KD, sND, sND, sNN, 0.03125f);
    // 7. p = softmax(sc)  -> S1 (q dead)
    softmax_split_kernel<<<ROWS, blk, 0, stream>>>(sc, S1h, S1l);
    // 8. attV = p @ vT^T  (batched; B = vT + bz*1024, ldb=ROWS) -> S0 (sc dead)
    gemm_mfma<0, false, true, false><<<ga, blk, 0, stream>>>(
        S1h, S1l, S2h, S2l, nullptr, nullptr, nullptr, S0h, S0l, DIM, ROWS, sNN, SEQ, sND, 1.0f);
    // 9. x_update = attV @ wo + bo + x  -> xupd in ws (S1; p dead)
    gemm_mfma<1, false, false, true><<<gw, blk, 0, stream>>>(
        S0h, S0l, wTh[3], wTl[3], bo, x, xupd, nullptr, nullptr, DIM, KD, 0, 0, 0, 1.0f);
    // 10. xu = LN2(x_update)  -> S0 (attV dead)
    ln_split_kernel<<<ROWS, blk, 0, stream>>>(xupd, ln2_g, ln2_b, S0h, S0l);
    // 11. h1 = gelu(xu @ w1 + b1)  -> S2 (vT dead)
    gemm_mfma<1, true, true, false><<<gw, blk, 0, stream>>>(
        S0h, S0l, wTh[4], wTl[4], b1, nullptr, nullptr, S2h, S2l, DIM, KD, 0, 0, 0, 1.0f);
    // 12. out = gelu(h1 @ w2 + b2) + x_update  -> d_out (single full write)
    gemm_mfma<1, true, false, true><<<gw, blk, 0, stream>>>(
        S2h, S2l, wTh[5], wTl[5], b2, xupd, (float*)d_out, nullptr, nullptr, DIM, KD, 0, 0, 0, 1.0f);
}